// Round 1
// baseline (3365.861 us; speedup 1.0000x reference)
//
#include <hip/hip_runtime.h>
#include <cstdint>

#define BN_EPS 1e-5f

// ---------------------------------------------------------------------------
// Tiled fp32 GEMM: C[M x 128] = scale(A[M x K]) @ W[128 x K]^T (+ epilogue)
// EPI=true: +bias, PReLU, accumulate per-feature sum/sumsq for BN (training).
// cnt != nullptr: each A row is scaled by 1/max(cnt[row],1) (segment mean).
// May run in-place (C == A) when K == 128: each block fully reads its own
// rows across all k-tiles before the epilogue writes them; rows are disjoint
// across blocks.
// ---------------------------------------------------------------------------
template<int K, bool EPI>
__global__ __launch_bounds__(256) void gemm_kernel(
    const float* __restrict__ A,
    const float* __restrict__ W,      // [128, K] row-major
    const float* __restrict__ cnt,    // [M] or nullptr
    const float* __restrict__ bias,   // [128] or nullptr
    const float* __restrict__ prelu_a,// [1] or nullptr
    float* __restrict__ C,            // [M, 128]
    float* __restrict__ bnsum,
    float* __restrict__ bnsumsq,
    int M)
{
    constexpr int BM = 64, BN = 128, BK = 32;
    __shared__ float aT[BK][BM + 4];
    __shared__ float wT[BK][BN];
    __shared__ float red_s[BN];
    __shared__ float red_q[BN];

    const int tid = threadIdx.x;
    const int tx = tid & 31;   // col group: cols 4*tx .. 4*tx+3
    const int ty = tid >> 5;   // row group: rows 8*ty .. 8*ty+7
    const int row0 = blockIdx.x * BM;

    float acc[8][4];
#pragma unroll
    for (int r = 0; r < 8; ++r)
#pragma unroll
        for (int c = 0; c < 4; ++c) acc[r][c] = 0.f;

    for (int k0 = 0; k0 < K; k0 += BK) {
        // ---- stage A tile (64 rows x 32 k), transposed, with 1/cnt folded in
#pragma unroll
        for (int rep = 0; rep < 2; ++rep) {
            int r  = (tid >> 3) + rep * 32;  // 0..63
            int kq = tid & 7;                // k = 4*kq .. 4*kq+3
            int grow = row0 + r;
            float4 v = make_float4(0.f, 0.f, 0.f, 0.f);
            float s = 1.f;
            if (grow < M) {
                v = *(const float4*)(A + (size_t)grow * K + k0 + 4 * kq);
                if (cnt) s = 1.f / fmaxf(cnt[grow], 1.f);
            }
            aT[4*kq+0][r] = v.x * s;
            aT[4*kq+1][r] = v.y * s;
            aT[4*kq+2][r] = v.z * s;
            aT[4*kq+3][r] = v.w * s;
        }
        // ---- stage W tile (128 cols x 32 k), transposed
#pragma unroll
        for (int rep = 0; rep < 4; ++rep) {
            int j  = tid & 127;
            int kh = tid >> 7;               // 0..1
            int kk = kh * 16 + rep * 4;      // covers k 0..31
            float4 v = *(const float4*)(W + (size_t)j * K + k0 + kk);
            wT[kk+0][j] = v.x;
            wT[kk+1][j] = v.y;
            wT[kk+2][j] = v.z;
            wT[kk+3][j] = v.w;
        }
        __syncthreads();
#pragma unroll
        for (int k = 0; k < BK; ++k) {
            float4 w4 = *(const float4*)&wT[k][4*tx];
            float4 a0 = *(const float4*)&aT[k][8*ty];
            float4 a1 = *(const float4*)&aT[k][8*ty+4];
            float av[8] = {a0.x,a0.y,a0.z,a0.w,a1.x,a1.y,a1.z,a1.w};
            float wv[4] = {w4.x,w4.y,w4.z,w4.w};
#pragma unroll
            for (int r = 0; r < 8; ++r)
#pragma unroll
                for (int c = 0; c < 4; ++c)
                    acc[r][c] = fmaf(av[r], wv[c], acc[r][c]);
        }
        __syncthreads();
    }

    if (!EPI) {
#pragma unroll
        for (int r = 0; r < 8; ++r) {
            int grow = row0 + 8*ty + r;
            if (grow < M) {
                float4 o = make_float4(acc[r][0], acc[r][1], acc[r][2], acc[r][3]);
                *(float4*)(C + (size_t)grow * BN + 4*tx) = o;
            }
        }
    } else {
        float b[4];
#pragma unroll
        for (int c = 0; c < 4; ++c) b[c] = bias[4*tx + c];
        float pa = prelu_a[0];
        if (tid < BN) { red_s[tid] = 0.f; red_q[tid] = 0.f; }
        __syncthreads();
        float lsum[4] = {0,0,0,0}, lsq[4] = {0,0,0,0};
#pragma unroll
        for (int r = 0; r < 8; ++r) {
            int grow = row0 + 8*ty + r;
            if (grow < M) {
                float vv[4];
#pragma unroll
                for (int c = 0; c < 4; ++c) {
                    float v = acc[r][c] + b[c];
                    v = (v >= 0.f) ? v : pa * v;   // PReLU
                    vv[c] = v;
                    lsum[c] += v;
                    lsq[c]  += v * v;
                }
                float4 o = make_float4(vv[0], vv[1], vv[2], vv[3]);
                *(float4*)(C + (size_t)grow * BN + 4*tx) = o;
            }
        }
#pragma unroll
        for (int c = 0; c < 4; ++c) {
            atomicAdd(&red_s[4*tx + c], lsum[c]);
            atomicAdd(&red_q[4*tx + c], lsq[c]);
        }
        __syncthreads();
        if (tid < BN) {
            atomicAdd(&bnsum[tid],   red_s[tid]);
            atomicAdd(&bnsumsq[tid], red_q[tid]);
        }
    }
}

// ---------------------------------------------------------------------------
// fused[e] = edge_attr[e] + 0.5*(px[src[e]] + px[dst[e]])   (float4 elements)
// ---------------------------------------------------------------------------
__global__ __launch_bounds__(256) void fuse_kernel(
    const float* __restrict__ edge_attr, const float* __restrict__ px,
    const int* __restrict__ src, const int* __restrict__ dst,
    float* __restrict__ fused, int E)
{
    size_t i = (size_t)blockIdx.x * blockDim.x + threadIdx.x;
    size_t total = (size_t)E * 32;   // float4s per edge row (128 floats)
    if (i >= total) return;
    int e = (int)(i >> 5);
    int q = (int)(i & 31);
    int s = src[e], d = dst[e];
    float4 ea = ((const float4*)edge_attr)[i];
    float4 ps = ((const float4*)px)[(size_t)s * 32 + q];
    float4 pd = ((const float4*)px)[(size_t)d * 32 + q];
    float4 o;
    o.x = ea.x + 0.5f * (ps.x + pd.x);
    o.y = ea.y + 0.5f * (ps.y + pd.y);
    o.z = ea.z + 0.5f * (ps.z + pd.z);
    o.w = ea.w + 0.5f * (ps.w + pd.w);
    ((float4*)fused)[i] = o;
}

// ---------------------------------------------------------------------------
// Line-graph scatter-add: agg[ld[l]] += fused[ls[l]]; cntl[ld[l]] += 1
// One wave (64 lanes) per line edge; float2 per lane (128 floats/row).
// ---------------------------------------------------------------------------
__global__ __launch_bounds__(256) void scatter_line_kernel(
    const float* __restrict__ fused,
    const int* __restrict__ ls, const int* __restrict__ ld,
    float* __restrict__ agg, float* __restrict__ cntl, int L)
{
    int w = (int)(((size_t)blockIdx.x * blockDim.x + threadIdx.x) >> 6);
    int lane = threadIdx.x & 63;
    if (w >= L) return;
    int s = ls[w], d = ld[w];
    float2 v = ((const float2*)(fused + (size_t)s * 128))[lane];
    float* dp = agg + (size_t)d * 128 + 2 * lane;
    atomicAdd(dp,     v.x);
    atomicAdd(dp + 1, v.y);
    if (lane == 0) atomicAdd(cntl + d, 1.f);
}

// ---------------------------------------------------------------------------
// BN finalize: cA = gamma/sqrt(var+eps); cB = beta - mean*cA
// ---------------------------------------------------------------------------
__global__ void bn_finalize_kernel(
    const float* __restrict__ bnsum, const float* __restrict__ bnsumsq,
    const float* __restrict__ gamma, const float* __restrict__ beta,
    float* __restrict__ cA, float* __restrict__ cB, float invE)
{
    int c = threadIdx.x;  // 128 threads
    float mean = bnsum[c] * invE;
    float var  = bnsumsq[c] * invE - mean * mean;
    float istd = 1.f / sqrtf(var + BN_EPS);
    float a = istd * gamma[c];
    cA[c] = a;
    cB[c] = beta[c] - mean * a;
}

// ---------------------------------------------------------------------------
// Node scatter: out[dst[e]] += fused[e] + (h[e]*cA + cB); cntd[dst[e]] += 1
// ---------------------------------------------------------------------------
__global__ __launch_bounds__(256) void scatter_node_kernel(
    const float* __restrict__ fused, const float* __restrict__ h,
    const int* __restrict__ dsti,
    const float* __restrict__ cA, const float* __restrict__ cB,
    float* __restrict__ out, float* __restrict__ cntd, int E)
{
    int w = (int)(((size_t)blockIdx.x * blockDim.x + threadIdx.x) >> 6);
    int lane = threadIdx.x & 63;
    if (w >= E) return;
    int d = dsti[w];
    float2 f  = ((const float2*)(fused + (size_t)w * 128))[lane];
    float2 hh = ((const float2*)(h     + (size_t)w * 128))[lane];
    float2 A  = ((const float2*)cA)[lane];
    float2 B  = ((const float2*)cB)[lane];
    float v0 = f.x + fmaf(hh.x, A.x, B.x);
    float v1 = f.y + fmaf(hh.y, A.y, B.y);
    float* op = out + (size_t)d * 128 + 2 * lane;
    atomicAdd(op,     v0);
    atomicAdd(op + 1, v1);
    if (lane == 0) atomicAdd(cntd + d, 1.f);
}

// ---------------------------------------------------------------------------
// out[n][:] /= max(cntd[n], 1)
// ---------------------------------------------------------------------------
__global__ __launch_bounds__(256) void div_kernel(
    float* __restrict__ out, const float* __restrict__ cntd, int N)
{
    int i = blockIdx.x * blockDim.x + threadIdx.x;
    if (i >= N * 128) return;
    out[i] = out[i] / fmaxf(cntd[i >> 7], 1.f);
}

// ---------------------------------------------------------------------------
extern "C" void kernel_launch(void* const* d_in, const int* in_sizes, int n_in,
                              void* d_out, int out_size, void* d_ws, size_t ws_size,
                              hipStream_t stream) {
    const float* x     = (const float*)d_in[0];
    const float* ea    = (const float*)d_in[1];
    const float* Wp    = (const float*)d_in[2];  // [128, 256]
    const float* W1    = (const float*)d_in[3];  // [128, 128]
    const float* b1    = (const float*)d_in[4];
    const float* pa    = (const float*)d_in[5];
    const float* gamma = (const float*)d_in[6];
    const float* beta  = (const float*)d_in[7];
    const int*   ei    = (const int*)d_in[8];
    const int*   lg    = (const int*)d_in[9];

    const int ND = 256, ED = 128;
    const int N = in_sizes[0] / ND;   // 50000
    const int E = in_sizes[1] / ED;   // 800000
    const int L = in_sizes[9] / 2;    // 1600000
    const int* src  = ei;
    const int* dstI = ei + E;
    const int* ls   = lg;
    const int* ld   = lg + L;

    float* ws = (float*)d_ws;
    size_t off = 0;
    float* px    = ws + off; off += (size_t)N * ED;   // 6.4M
    float* fused = ws + off; off += (size_t)E * ED;   // 102.4M
    float* aggh  = ws + off; off += (size_t)E * ED;   // 102.4M (agg, then h in-place)
    float* cntl  = ws + off; off += (size_t)E;
    float* cntd  = ws + off; off += (size_t)N;
    float* bnsum = ws + off; off += ED;
    float* bnsq  = ws + off; off += ED;
    float* cA    = ws + off; off += ED;
    float* cB    = ws + off; off += ED;

    float* out = (float*)d_out;

    hipMemsetAsync(aggh,  0, (size_t)E * ED * sizeof(float), stream);
    hipMemsetAsync(cntl,  0, (size_t)E * sizeof(float), stream);
    hipMemsetAsync(cntd,  0, (size_t)N * sizeof(float), stream);
    hipMemsetAsync(bnsum, 0, 2 * ED * sizeof(float), stream);   // bnsum+bnsq contiguous
    hipMemsetAsync(out,   0, (size_t)N * ED * sizeof(float), stream);

    // K1: px = x @ Wp^T
    gemm_kernel<256, false><<<(N + 63) / 64, 256, 0, stream>>>(
        x, Wp, nullptr, nullptr, nullptr, px, nullptr, nullptr, N);

    // K2: fused
    {
        size_t tot = (size_t)E * 32;
        fuse_kernel<<<(int)((tot + 255) / 256), 256, 0, stream>>>(ea, px, src, dstI, fused, E);
    }

    // K3: line-graph scatter-add (+ counts)
    scatter_line_kernel<<<(L + 3) / 4, 256, 0, stream>>>(fused, ls, ld, aggh, cntl, L);

    // K4: h = (agg/cnt) @ W1^T + b1 -> PReLU -> (in-place over agg) + BN sums
    gemm_kernel<128, true><<<(E + 63) / 64, 256, 0, stream>>>(
        aggh, W1, cntl, b1, pa, aggh, bnsum, bnsq, E);

    // K4b: BN coefficients
    bn_finalize_kernel<<<1, 128, 0, stream>>>(bnsum, bnsq, gamma, beta, cA, cB, 1.f / (float)E);

    // K5: normalize + residual + scatter-mean to nodes (accumulate)
    scatter_node_kernel<<<(E + 3) / 4, 256, 0, stream>>>(fused, aggh, dstI, cA, cB, out, cntd, E);

    // K6: divide by node counts
    div_kernel<<<(N * ED + 255) / 256, 256, 0, stream>>>(out, cntd, N);
}

// Round 2
// 2107.238 us; speedup vs baseline: 1.5973x; 1.5973x over previous
//
#include <hip/hip_runtime.h>
#include <cstdint>

#define BN_EPS 1e-5f

// ---------------------------------------------------------------------------
// Tiled fp32 GEMM: C[M x 128] = A[M x K] @ W[128 x K]^T (+ epilogue)
// EPI=true: +bias, PReLU, accumulate per-feature sum/sumsq for BN (training).
// May run in-place (C == A) when K == 128: each block fully reads its own
// rows across all k-tiles before the epilogue writes them; rows are disjoint
// across blocks.
// ---------------------------------------------------------------------------
template<int K, bool EPI>
__global__ __launch_bounds__(256) void gemm_kernel(
    const float* __restrict__ A,
    const float* __restrict__ W,      // [128, K] row-major
    const float* __restrict__ bias,   // [128] or nullptr
    const float* __restrict__ prelu_a,// [1] or nullptr
    float* __restrict__ C,            // [M, 128]
    float* __restrict__ bnsum,
    float* __restrict__ bnsumsq,
    int M)
{
    constexpr int BM = 64, BN = 128, BK = 32;
    __shared__ float aT[BK][BM + 4];
    __shared__ float wT[BK][BN];
    __shared__ float red_s[BN];
    __shared__ float red_q[BN];

    const int tid = threadIdx.x;
    const int tx = tid & 31;   // col group: cols 4*tx .. 4*tx+3
    const int ty = tid >> 5;   // row group: rows 8*ty .. 8*ty+7
    const int row0 = blockIdx.x * BM;

    float acc[8][4];
#pragma unroll
    for (int r = 0; r < 8; ++r)
#pragma unroll
        for (int c = 0; c < 4; ++c) acc[r][c] = 0.f;

    for (int k0 = 0; k0 < K; k0 += BK) {
        // ---- stage A tile (64 rows x 32 k), transposed
#pragma unroll
        for (int rep = 0; rep < 2; ++rep) {
            int r  = (tid >> 3) + rep * 32;  // 0..63
            int kq = tid & 7;                // k = 4*kq .. 4*kq+3
            int grow = row0 + r;
            float4 v = make_float4(0.f, 0.f, 0.f, 0.f);
            if (grow < M)
                v = *(const float4*)(A + (size_t)grow * K + k0 + 4 * kq);
            aT[4*kq+0][r] = v.x;
            aT[4*kq+1][r] = v.y;
            aT[4*kq+2][r] = v.z;
            aT[4*kq+3][r] = v.w;
        }
        // ---- stage W tile (128 cols x 32 k), transposed
#pragma unroll
        for (int rep = 0; rep < 4; ++rep) {
            int j  = tid & 127;
            int kh = tid >> 7;               // 0..1
            int kk = kh * 16 + rep * 4;      // covers k 0..31
            float4 v = *(const float4*)(W + (size_t)j * K + k0 + kk);
            wT[kk+0][j] = v.x;
            wT[kk+1][j] = v.y;
            wT[kk+2][j] = v.z;
            wT[kk+3][j] = v.w;
        }
        __syncthreads();
#pragma unroll
        for (int k = 0; k < BK; ++k) {
            float4 w4 = *(const float4*)&wT[k][4*tx];
            float4 a0 = *(const float4*)&aT[k][8*ty];
            float4 a1 = *(const float4*)&aT[k][8*ty+4];
            float av[8] = {a0.x,a0.y,a0.z,a0.w,a1.x,a1.y,a1.z,a1.w};
            float wv[4] = {w4.x,w4.y,w4.z,w4.w};
#pragma unroll
            for (int r = 0; r < 8; ++r)
#pragma unroll
                for (int c = 0; c < 4; ++c)
                    acc[r][c] = fmaf(av[r], wv[c], acc[r][c]);
        }
        __syncthreads();
    }

    if (!EPI) {
#pragma unroll
        for (int r = 0; r < 8; ++r) {
            int grow = row0 + 8*ty + r;
            if (grow < M) {
                float4 o = make_float4(acc[r][0], acc[r][1], acc[r][2], acc[r][3]);
                *(float4*)(C + (size_t)grow * BN + 4*tx) = o;
            }
        }
    } else {
        float b[4];
#pragma unroll
        for (int c = 0; c < 4; ++c) b[c] = bias[4*tx + c];
        float pa = prelu_a[0];
        if (tid < BN) { red_s[tid] = 0.f; red_q[tid] = 0.f; }
        __syncthreads();
        float lsum[4] = {0,0,0,0}, lsq[4] = {0,0,0,0};
#pragma unroll
        for (int r = 0; r < 8; ++r) {
            int grow = row0 + 8*ty + r;
            if (grow < M) {
                float vv[4];
#pragma unroll
                for (int c = 0; c < 4; ++c) {
                    float v = acc[r][c] + b[c];
                    v = (v >= 0.f) ? v : pa * v;   // PReLU
                    vv[c] = v;
                    lsum[c] += v;
                    lsq[c]  += v * v;
                }
                float4 o = make_float4(vv[0], vv[1], vv[2], vv[3]);
                *(float4*)(C + (size_t)grow * BN + 4*tx) = o;
            }
        }
#pragma unroll
        for (int c = 0; c < 4; ++c) {
            atomicAdd(&red_s[4*tx + c], lsum[c]);
            atomicAdd(&red_q[4*tx + c], lsq[c]);
        }
        __syncthreads();
        if (tid < BN) {
            atomicAdd(&bnsum[tid],   red_s[tid]);
            atomicAdd(&bnsumsq[tid], red_q[tid]);
        }
    }
}

// ---------------------------------------------------------------------------
// fused[e] = edge_attr[e] + 0.5*(px[src[e]] + px[dst[e]])   (float4 elements)
// ---------------------------------------------------------------------------
__global__ __launch_bounds__(256) void fuse_kernel(
    const float* __restrict__ edge_attr, const float* __restrict__ px,
    const int* __restrict__ src, const int* __restrict__ dst,
    float* __restrict__ fused, int E)
{
    size_t i = (size_t)blockIdx.x * blockDim.x + threadIdx.x;
    size_t total = (size_t)E * 32;   // float4s per edge row (128 floats)
    if (i >= total) return;
    int e = (int)(i >> 5);
    int q = (int)(i & 31);
    int s = src[e], d = dst[e];
    float4 ea = ((const float4*)edge_attr)[i];
    float4 ps = ((const float4*)px)[(size_t)s * 32 + q];
    float4 pd = ((const float4*)px)[(size_t)d * 32 + q];
    float4 o;
    o.x = ea.x + 0.5f * (ps.x + pd.x);
    o.y = ea.y + 0.5f * (ps.y + pd.y);
    o.z = ea.z + 0.5f * (ps.z + pd.z);
    o.w = ea.w + 0.5f * (ps.w + pd.w);
    ((float4*)fused)[i] = o;
}

// ---------------------------------------------------------------------------
// CSR build: histogram -> block-scan -> global scan -> add+copy -> fill
// ---------------------------------------------------------------------------
__global__ __launch_bounds__(256) void hist_kernel(
    const int* __restrict__ idx, int* __restrict__ deg, int n)
{
    int i = blockIdx.x * 256 + threadIdx.x;
    if (i < n) atomicAdd(&deg[idx[i]], 1);
}

// Pass 1: per-block (2048 elems) exclusive scan + block totals.
__global__ __launch_bounds__(256) void scan_local_kernel(
    const int* __restrict__ deg, int* __restrict__ excl,
    int* __restrict__ bsum, int n)
{
    __shared__ int ts[256];
    int t = threadIdx.x;
    int base = blockIdx.x * 2048 + t * 8;
    int v[8]; int s = 0;
#pragma unroll
    for (int j = 0; j < 8; ++j) { v[j] = (base + j < n) ? deg[base + j] : 0; s += v[j]; }
    ts[t] = s; __syncthreads();
    for (int off = 1; off < 256; off <<= 1) {
        int x = (t >= off) ? ts[t - off] : 0;
        __syncthreads();
        ts[t] += x;
        __syncthreads();
    }
    if (t == 255) bsum[blockIdx.x] = ts[255];
    int run = ts[t] - s;   // exclusive prefix for this thread within block
#pragma unroll
    for (int j = 0; j < 8; ++j) {
        if (base + j < n) excl[base + j] = run;
        run += v[j];
    }
}

// Pass 2: exclusive scan of block totals (single block, chunked).
__global__ __launch_bounds__(256) void scan_blocks_kernel(int* __restrict__ bsum, int nb)
{
    __shared__ int ts[256];
    __shared__ int carry_s;
    int t = threadIdx.x;
    if (t == 0) carry_s = 0;
    __syncthreads();
    for (int c0 = 0; c0 < nb; c0 += 256) {
        int v = (c0 + t < nb) ? bsum[c0 + t] : 0;
        ts[t] = v; __syncthreads();
        for (int off = 1; off < 256; off <<= 1) {
            int x = (t >= off) ? ts[t - off] : 0;
            __syncthreads();
            ts[t] += x;
            __syncthreads();
        }
        int carry = carry_s;
        if (c0 + t < nb) bsum[c0 + t] = carry + ts[t] - v;
        int tot = ts[255];
        __syncthreads();
        if (t == 0) carry_s = carry + tot;
        __syncthreads();
    }
}

// Pass 3: add block offsets; copy to cursor; write rowptr[n] = total.
__global__ __launch_bounds__(256) void scan_add_kernel(
    int* __restrict__ rowptr, const int* __restrict__ bsum,
    int* __restrict__ cursor, int n, int total)
{
    int i = blockIdx.x * 256 + threadIdx.x;
    if (i == 0) rowptr[n] = total;
    if (i >= n) return;
    int v = rowptr[i] + bsum[i >> 11];
    rowptr[i] = v;
    cursor[i] = v;
}

// Fill adjacency: adj[pos] = vals ? vals[i] : i, bucketed by dsti[i].
__global__ __launch_bounds__(256) void fill_kernel(
    const int* __restrict__ dsti, const int* __restrict__ vals,
    int* __restrict__ cursor, int* __restrict__ adj, int n)
{
    int i = blockIdx.x * 256 + threadIdx.x;
    if (i >= n) return;
    int pos = atomicAdd(&cursor[dsti[i]], 1);
    adj[pos] = vals ? vals[i] : i;
}

// ---------------------------------------------------------------------------
// agg[e] = mean over incoming line-edges of fused[src]; one wave per edge.
// ---------------------------------------------------------------------------
__global__ __launch_bounds__(256) void gather_line_kernel(
    const float* __restrict__ fused, const int* __restrict__ rowptr,
    const int* __restrict__ adj, float* __restrict__ agg, int E)
{
    int w = (int)(((size_t)blockIdx.x * 256 + threadIdx.x) >> 6);
    int lane = threadIdx.x & 63;
    if (w >= E) return;
    int s0 = rowptr[w], s1 = rowptr[w + 1];
    float2 acc = make_float2(0.f, 0.f);
    for (int j = s0; j < s1; ++j) {
        int s = adj[j];
        float2 v = ((const float2*)(fused + (size_t)s * 128))[lane];
        acc.x += v.x; acc.y += v.y;
    }
    float scl = 1.f / fmaxf((float)(s1 - s0), 1.f);
    ((float2*)(agg + (size_t)w * 128))[lane] = make_float2(acc.x * scl, acc.y * scl);
}

// ---------------------------------------------------------------------------
// BN finalize: cA = gamma/sqrt(var+eps); cB = beta - mean*cA
// ---------------------------------------------------------------------------
__global__ void bn_finalize_kernel(
    const float* __restrict__ bnsum, const float* __restrict__ bnsumsq,
    const float* __restrict__ gamma, const float* __restrict__ beta,
    float* __restrict__ cA, float* __restrict__ cB, float invE)
{
    int c = threadIdx.x;  // 128 threads
    float mean = bnsum[c] * invE;
    float var  = bnsumsq[c] * invE - mean * mean;
    float istd = 1.f / sqrtf(var + BN_EPS);
    float a = istd * gamma[c];
    cA[c] = a;
    cB[c] = beta[c] - mean * a;
}

// ---------------------------------------------------------------------------
// out[n] = mean over incident edges of (fused[e] + h[e]*cA + cB);
// one wave per node.
// ---------------------------------------------------------------------------
__global__ __launch_bounds__(256) void gather_node_kernel(
    const float* __restrict__ fused, const float* __restrict__ h,
    const int* __restrict__ rowptr, const int* __restrict__ adj,
    const float* __restrict__ cA, const float* __restrict__ cB,
    float* __restrict__ out, int N)
{
    int w = (int)(((size_t)blockIdx.x * 256 + threadIdx.x) >> 6);
    int lane = threadIdx.x & 63;
    if (w >= N) return;
    int s0 = rowptr[w], s1 = rowptr[w + 1];
    float2 A = ((const float2*)cA)[lane];
    float2 B = ((const float2*)cB)[lane];
    float2 acc = make_float2(0.f, 0.f);
    for (int j = s0; j < s1; ++j) {
        int e = adj[j];
        float2 f  = ((const float2*)(fused + (size_t)e * 128))[lane];
        float2 hh = ((const float2*)(h     + (size_t)e * 128))[lane];
        acc.x += f.x + fmaf(hh.x, A.x, B.x);
        acc.y += f.y + fmaf(hh.y, A.y, B.y);
    }
    float scl = 1.f / fmaxf((float)(s1 - s0), 1.f);
    ((float2*)(out + (size_t)w * 128))[lane] = make_float2(acc.x * scl, acc.y * scl);
}

// ---------------------------------------------------------------------------
extern "C" void kernel_launch(void* const* d_in, const int* in_sizes, int n_in,
                              void* d_out, int out_size, void* d_ws, size_t ws_size,
                              hipStream_t stream) {
    const float* x     = (const float*)d_in[0];
    const float* ea    = (const float*)d_in[1];
    const float* Wp    = (const float*)d_in[2];  // [128, 256]
    const float* W1    = (const float*)d_in[3];  // [128, 128]
    const float* b1    = (const float*)d_in[4];
    const float* pa    = (const float*)d_in[5];
    const float* gamma = (const float*)d_in[6];
    const float* beta  = (const float*)d_in[7];
    const int*   ei    = (const int*)d_in[8];
    const int*   lg    = (const int*)d_in[9];

    const int ND = 256, ED = 128;
    const int N = in_sizes[0] / ND;   // 50000
    const int E = in_sizes[1] / ED;   // 800000
    const int L = in_sizes[9] / 2;    // 1600000
    const int* src  = ei;
    const int* dstI = ei + E;
    const int* ls   = lg;
    const int* ld   = lg + L;

    float* ws = (float*)d_ws;
    size_t off = 0;
    float* px    = ws + off; off += (size_t)N * ED;       // 6.4M
    float* fused = ws + off; off += (size_t)E * ED;       // 102.4M
    float* aggh  = ws + off; off += (size_t)E * ED;       // 102.4M (agg, then h in-place)
    float* bnsum = ws + off; off += ED;
    float* bnsq  = ws + off; off += ED;
    float* cA    = ws + off; off += ED;
    float* cB    = ws + off; off += ED;

    int* iws = (int*)(ws + off);
    size_t ioff = 0;
    int* deg_l  = iws + ioff; ioff += E;        // reused as cursor
    int* rp_l   = iws + ioff; ioff += E + 1;
    int* adj_l  = iws + ioff; ioff += L;
    int* bs_l   = iws + ioff; ioff += 1024;
    int* deg_n  = iws + ioff; ioff += N;        // reused as cursor
    int* rp_n   = iws + ioff; ioff += N + 1;
    int* adj_n  = iws + ioff; ioff += E;
    int* bs_n   = iws + ioff; ioff += 1024;

    float* out = (float*)d_out;

    const int nb_l = (E + 2047) / 2048;   // scan blocks for line CSR
    const int nb_n = (N + 2047) / 2048;   // scan blocks for node CSR

    // ---- zero the small accumulators
    hipMemsetAsync(bnsum, 0, 2 * ED * sizeof(float), stream);  // bnsum+bnsq
    hipMemsetAsync(deg_l, 0, (size_t)E * sizeof(int), stream);
    hipMemsetAsync(deg_n, 0, (size_t)N * sizeof(int), stream);

    // K1: px = x @ Wp^T
    gemm_kernel<256, false><<<(N + 63) / 64, 256, 0, stream>>>(
        x, Wp, nullptr, nullptr, px, nullptr, nullptr, N);

    // K2: fused = edge_attr + 0.5*(px[src]+px[dst])
    {
        size_t tot = (size_t)E * 32;
        fuse_kernel<<<(int)((tot + 255) / 256), 256, 0, stream>>>(ea, px, src, dstI, fused, E);
    }

    // ---- line-graph CSR (bucket by destination edge ld)
    hist_kernel<<<(L + 255) / 256, 256, 0, stream>>>(ld, deg_l, L);
    scan_local_kernel<<<nb_l, 256, 0, stream>>>(deg_l, rp_l, bs_l, E);
    scan_blocks_kernel<<<1, 256, 0, stream>>>(bs_l, nb_l);
    scan_add_kernel<<<(E + 255) / 256, 256, 0, stream>>>(rp_l, bs_l, deg_l, E, L);
    fill_kernel<<<(L + 255) / 256, 256, 0, stream>>>(ld, ls, deg_l, adj_l, L);

    // ---- node CSR (bucket by dst)
    hist_kernel<<<(E + 255) / 256, 256, 0, stream>>>(dstI, deg_n, E);
    scan_local_kernel<<<nb_n, 256, 0, stream>>>(deg_n, rp_n, bs_n, N);
    scan_blocks_kernel<<<1, 256, 0, stream>>>(bs_n, nb_n);
    scan_add_kernel<<<(N + 255) / 256, 256, 0, stream>>>(rp_n, bs_n, deg_n, N, E);
    fill_kernel<<<(E + 255) / 256, 256, 0, stream>>>(dstI, nullptr, deg_n, adj_n, E);

    // K3: agg = segment-mean of fused over line graph (no atomics)
    gather_line_kernel<<<(E + 3) / 4, 256, 0, stream>>>(fused, rp_l, adj_l, aggh, E);

    // K4: h = agg @ W1^T + b1 -> PReLU (in-place over agg) + BN sums
    gemm_kernel<128, true><<<(E + 63) / 64, 256, 0, stream>>>(
        aggh, W1, b1, pa, aggh, bnsum, bnsq, E);

    // K4b: BN coefficients
    bn_finalize_kernel<<<1, 128, 0, stream>>>(bnsum, bnsq, gamma, beta, cA, cB, 1.f / (float)E);

    // K5: out = segment-mean over dst of (fused + BN(h))  (no atomics)
    gather_node_kernel<<<(N + 3) / 4, 256, 0, stream>>>(fused, aggh, rp_n, adj_n, cA, cB, out, N);
}